// Round 7
// baseline (976.499 us; speedup 1.0000x reference)
//
#include <hip/hip_runtime.h>

#define BB   2048
#define SS   256
#define NTOK (BB*SS)
#define FIN  3
#define CND  4
#define EMB  4
#define HID  64
#define NC   256
#define TPB  256   // T=2 tokens/thread: block covers 512 tokens

typedef float f2 __attribute__((ext_vector_type(2)));
#define VFMA(a,b,c) __builtin_elementwise_fma(a,b,c)

static __device__ __forceinline__ f2 sp(float v) { f2 r; r.x = v; r.y = v; return r; }
static __device__ __forceinline__ f2 vrelu(f2 v) { return __builtin_elementwise_max(v, sp(0.0f)); }

// Fused LDS layout (float offsets; float4-aligned where float4-read). 44.7 KB.
#define OF_EW1 0        // 448
#define OF_EB1 448      // 64
#define OF_EW2 512      // 4096
#define OF_EB2 4608     // 64
#define OF_EW3 4672     // 256
#define OF_EB3 4928     // 4 (pad to 4944)
#define OF_CB  4944     // 1024
#define OF_CC  5968     // 256
#define OF_DW1 6224     // 512
#define OF_DB1 6736     // 64
#define OF_DW2 6800     // 4096
#define OF_DB2 10896    // 64
#define OF_DW3 10960    // 192
#define OF_DB3 11152    // 4
#define SMEM_F 11168    // 44672 B

// Launch-bounds history: (256,6)->85-reg cap = spill disaster (R4).
// (256,2)->VGPR+AGPR ~256/wave -> only 2 waves/SIMD, latency-bound (R6).
// (256,3)->170-reg cap vs ~160 live: 3 waves/SIMD, no spill (watch FETCH_SIZE).
__global__ __launch_bounds__(TPB, 3) void vqvae_fused(
        const float* __restrict__ x, const float* __restrict__ mask,
        const float* __restrict__ cond,
        const float* __restrict__ ew1, const float* __restrict__ eb1,
        const float* __restrict__ ew2, const float* __restrict__ eb2,
        const float* __restrict__ ew3, const float* __restrict__ eb3,
        const float* __restrict__ cb,
        const float* __restrict__ dw1, const float* __restrict__ db1,
        const float* __restrict__ dw2, const float* __restrict__ db2,
        const float* __restrict__ dw3, const float* __restrict__ db3,
        float* __restrict__ out, float* __restrict__ ws) {
    __shared__ float smem[SMEM_F];
    const int tid = threadIdx.x;

    for (int i = tid; i < (FIN+CND)*HID; i += TPB) smem[OF_EW1+i] = ew1[i];
    for (int i = tid; i < HID;           i += TPB) smem[OF_EB1+i] = eb1[i];
    for (int i = tid; i < HID*HID;       i += TPB) smem[OF_EW2+i] = ew2[i];
    for (int i = tid; i < HID;           i += TPB) smem[OF_EB2+i] = eb2[i];
    for (int i = tid; i < HID*EMB;       i += TPB) smem[OF_EW3+i] = ew3[i];
    for (int i = tid; i < EMB;           i += TPB) smem[OF_EB3+i] = eb3[i];
    for (int i = tid; i < NC*EMB;        i += TPB) smem[OF_CB +i] = cb[i];
    for (int i = tid; i < (EMB+CND)*HID; i += TPB) smem[OF_DW1+i] = dw1[i];
    for (int i = tid; i < HID;           i += TPB) smem[OF_DB1+i] = db1[i];
    for (int i = tid; i < HID*HID;       i += TPB) smem[OF_DW2+i] = dw2[i];
    for (int i = tid; i < HID;           i += TPB) smem[OF_DB2+i] = db2[i];
    for (int i = tid; i < HID*FIN;       i += TPB) smem[OF_DW3+i] = dw3[i];
    for (int i = tid; i < FIN;           i += TPB) smem[OF_DB3+i] = db3[i];
    {   // cc from GLOBAL cb (no barrier dependency); tid in [0,256) covers NC
        float c0 = cb[tid*EMB+0], c1 = cb[tid*EMB+1];
        float c2 = cb[tid*EMB+2], c3 = cb[tid*EMB+3];
        smem[OF_CC+tid] = ((c0*c0 + c1*c1) + c2*c2) + c3*c3;  // validated order
    }
    __syncthreads();

    // two tokens per thread: lane-pair {A=n0, B=n1}; per-half math is
    // bit-identical to the validated scalar trees (explicit fma/add/max only).
    const int n0 = blockIdx.x * (2*TPB) + tid;
    const int n1 = n0 + TPB;
    f2 m; m.x = mask[n0]; m.y = mask[n1];
    const int bu0 = n0 >> 8;
    const int bu1 = bu0 + 1;

    f2 xin[FIN+CND];
    #pragma unroll
    for (int i = 0; i < FIN; i++) { xin[i].x = x[n0*FIN + i] * m.x; xin[i].y = x[n1*FIN + i] * m.y; }
    #pragma unroll
    for (int i = 0; i < CND; i++) { xin[FIN+i].x = cond[bu0*CND + i] * m.x; xin[FIN+i].y = cond[bu1*CND + i] * m.y; }

    // ---- encoder L1: 7 -> 64, relu ----
    f2 h[HID];
    #pragma unroll
    for (int j = 0; j < HID; j++) {
        f2 a = xin[0] * sp(smem[OF_EW1 + j]);
        #pragma unroll
        for (int i = 1; i < FIN+CND; i++) a = VFMA(xin[i], sp(smem[OF_EW1 + i*HID + j]), a);
        h[j] = vrelu(a + sp(smem[OF_EB1 + j]));
    }

    // ---- encoder L2 (relu) fused with L3 fold ----
    f2 z0 = sp(0.f), z1 = sp(0.f), z2 = sp(0.f), z3 = sp(0.f);
    for (int jt = 0; jt < 16; jt++) {
        f2 a0 = sp(0.f), a1 = sp(0.f), a2 = sp(0.f), a3 = sp(0.f);
        #pragma unroll
        for (int k = 0; k < HID; k++) {
            float4 w = *(const float4*)&smem[OF_EW2 + k*HID + jt*4];
            a0 = VFMA(h[k], sp(w.x), a0);
            a1 = VFMA(h[k], sp(w.y), a1);
            a2 = VFMA(h[k], sp(w.z), a2);
            a3 = VFMA(h[k], sp(w.w), a3);
        }
        float4 bb = *(const float4*)&smem[OF_EB2 + jt*4];
        f2 t0 = vrelu(a0 + sp(bb.x));
        f2 t1 = vrelu(a1 + sp(bb.y));
        f2 t2 = vrelu(a2 + sp(bb.z));
        f2 t3 = vrelu(a3 + sp(bb.w));
        float4 w0 = *(const float4*)&smem[OF_EW3 + (jt*4+0)*EMB];
        z0 = VFMA(t0, sp(w0.x), z0); z1 = VFMA(t0, sp(w0.y), z1);
        z2 = VFMA(t0, sp(w0.z), z2); z3 = VFMA(t0, sp(w0.w), z3);
        float4 w1 = *(const float4*)&smem[OF_EW3 + (jt*4+1)*EMB];
        z0 = VFMA(t1, sp(w1.x), z0); z1 = VFMA(t1, sp(w1.y), z1);
        z2 = VFMA(t1, sp(w1.z), z2); z3 = VFMA(t1, sp(w1.w), z3);
        float4 w2 = *(const float4*)&smem[OF_EW3 + (jt*4+2)*EMB];
        z0 = VFMA(t2, sp(w2.x), z0); z1 = VFMA(t2, sp(w2.y), z1);
        z2 = VFMA(t2, sp(w2.z), z2); z3 = VFMA(t2, sp(w2.w), z3);
        float4 w3 = *(const float4*)&smem[OF_EW3 + (jt*4+3)*EMB];
        z0 = VFMA(t3, sp(w3.x), z0); z1 = VFMA(t3, sp(w3.y), z1);
        z2 = VFMA(t3, sp(w3.z), z2); z3 = VFMA(t3, sp(w3.w), z3);
    }
    z0 = z0 + sp(smem[OF_EB3+0]); z1 = z1 + sp(smem[OF_EB3+1]);
    z2 = z2 + sp(smem[OF_EB3+2]); z3 = z3 + sp(smem[OF_EB3+3]);

    // ---- VQ argmin: kept SCALAR, textually identical to validated version
    // (zz/d expressions have fp-contract freedom; don't perturb codegen) ----
    const float A0 = z0.x, A1 = z1.x, A2 = z2.x, A3 = z3.x;
    const float B0 = z0.y, B1 = z1.y, B2 = z2.y, B3 = z3.y;
    const float zzA = ((A0*A0 + A1*A1) + A2*A2) + A3*A3;
    const float zzB = ((B0*B0 + B1*B1) + B2*B2) + B3*B3;
    float bestA = 3.4e38f, bestB = 3.4e38f;
    int   biA = 0, biB = 0;
    #pragma unroll 4
    for (int ci = 0; ci < NC; ci++) {
        float4 c = *(const float4*)&smem[OF_CB + ci*EMB];
        float cc = smem[OF_CC + ci];
        float dotA = A0 * c.x;
        dotA = fmaf(A1, c.y, dotA);
        dotA = fmaf(A2, c.z, dotA);
        dotA = fmaf(A3, c.w, dotA);
        float dA = (zzA - 2.0f*dotA) + cc;
        if (dA < bestA) { bestA = dA; biA = ci; }   // strict <: np first-min
        float dotB = B0 * c.x;
        dotB = fmaf(B1, c.y, dotB);
        dotB = fmaf(B2, c.z, dotB);
        dotB = fmaf(B3, c.w, dotB);
        float dB = (zzB - 2.0f*dotB) + cc;
        if (dB < bestB) { bestB = dB; biB = ci; }
    }
    float4 qA = *(const float4*)&smem[OF_CB + biA*EMB];
    float4 qB = *(const float4*)&smem[OF_CB + biB*EMB];

    // ---- vq loss partial ----
    float e0 = A0-qA.x, e1 = A1-qA.y, e2 = A2-qA.z, e3 = A3-qA.w;
    float f0 = B0-qB.x, f1 = B1-qB.y, f2_ = B2-qB.z, f3 = B3-qB.w;
    float sq = (((e0*e0 + e1*e1) + e2*e2) + e3*e3)
             + (((f0*f0 + f1*f1) + f2_*f2_) + f3*f3);
    #pragma unroll
    for (int off = 32; off > 0; off >>= 1) sq += __shfl_down(sq, off, 64);
    if ((tid & 63) == 0) atomicAdd(ws, sq);

    out[NTOK*FIN + 1 + n0] = (float)biA;
    out[NTOK*FIN + 1 + n1] = (float)biB;

    // ---- decoder input (refetch cond) ----
    f2 zd[EMB+CND];
    zd[0].x = qA.x*m.x; zd[0].y = qB.x*m.y;
    zd[1].x = qA.y*m.x; zd[1].y = qB.y*m.y;
    zd[2].x = qA.z*m.x; zd[2].y = qB.z*m.y;
    zd[3].x = qA.w*m.x; zd[3].y = qB.w*m.y;
    #pragma unroll
    for (int i = 0; i < CND; i++) { zd[EMB+i].x = cond[bu0*CND + i] * m.x; zd[EMB+i].y = cond[bu1*CND + i] * m.y; }

    // ---- decoder L1: 8 -> 64, relu (h reused) ----
    #pragma unroll
    for (int j = 0; j < HID; j++) {
        f2 a = zd[0] * sp(smem[OF_DW1 + j]);
        #pragma unroll
        for (int i = 1; i < EMB+CND; i++) a = VFMA(zd[i], sp(smem[OF_DW1 + i*HID + j]), a);
        h[j] = vrelu(a + sp(smem[OF_DB1 + j]));
    }

    // ---- decoder L2 (relu) fused with L3 ----
    f2 r0 = sp(0.f), r1 = sp(0.f), r2 = sp(0.f);
    for (int jt = 0; jt < 16; jt++) {
        f2 a0 = sp(0.f), a1 = sp(0.f), a2 = sp(0.f), a3 = sp(0.f);
        #pragma unroll
        for (int k = 0; k < HID; k++) {
            float4 w = *(const float4*)&smem[OF_DW2 + k*HID + jt*4];
            a0 = VFMA(h[k], sp(w.x), a0);
            a1 = VFMA(h[k], sp(w.y), a1);
            a2 = VFMA(h[k], sp(w.z), a2);
            a3 = VFMA(h[k], sp(w.w), a3);
        }
        float4 bb = *(const float4*)&smem[OF_DB2 + jt*4];
        f2 t0 = vrelu(a0 + sp(bb.x));
        f2 t1 = vrelu(a1 + sp(bb.y));
        f2 t2 = vrelu(a2 + sp(bb.z));
        f2 t3 = vrelu(a3 + sp(bb.w));
        #pragma unroll
        for (int jj = 0; jj < 4; jj++) {
            f2 t = (jj==0)?t0:(jj==1)?t1:(jj==2)?t2:t3;
            int j = jt*4 + jj;
            r0 = VFMA(t, sp(smem[OF_DW3 + j*FIN + 0]), r0);
            r1 = VFMA(t, sp(smem[OF_DW3 + j*FIN + 1]), r1);
            r2 = VFMA(t, sp(smem[OF_DW3 + j*FIN + 2]), r2);
        }
    }
    r0 = r0 + sp(smem[OF_DB3+0]);
    r1 = r1 + sp(smem[OF_DB3+1]);
    r2 = r2 + sp(smem[OF_DB3+2]);

    out[n0*FIN + 0] = r0.x;
    out[n0*FIN + 1] = r1.x;
    out[n0*FIN + 2] = r2.x;
    out[n1*FIN + 0] = r0.y;
    out[n1*FIN + 1] = r1.y;
    out[n1*FIN + 2] = r2.y;

    // ---- fused finalize: last block to finish writes vq_loss ----
    __syncthreads();                       // drains this block's atomics (vmcnt)
    if (tid == 0) {
        __threadfence();                   // loss adds visible before counter
        unsigned int old = atomicAdd((unsigned int*)(ws + 1), 1u);
        if (old == gridDim.x - 1) {
            __threadfence();
            float total = atomicAdd(ws, 0.0f);   // coherent read of final sum
            out[NTOK*FIN] = 1.25f * total * (1.0f / (float)(NTOK*EMB));
        }
    }
}

extern "C" void kernel_launch(void* const* d_in, const int* in_sizes, int n_in,
                              void* d_out, int out_size, void* d_ws, size_t ws_size,
                              hipStream_t stream) {
    (void)in_sizes; (void)n_in; (void)ws_size; (void)out_size;
    float* ws = (float*)d_ws;
    hipMemsetAsync(ws, 0, 2*sizeof(float), stream);  // loss accum + done counter

    vqvae_fused<<<NTOK/(2*TPB), TPB, 0, stream>>>(
        (const float*)d_in[0], (const float*)d_in[1], (const float*)d_in[2],
        (const float*)d_in[3], (const float*)d_in[4], (const float*)d_in[5],
        (const float*)d_in[6], (const float*)d_in[7], (const float*)d_in[8],
        (const float*)d_in[9], (const float*)d_in[10], (const float*)d_in[11],
        (const float*)d_in[12], (const float*)d_in[13], (const float*)d_in[14],
        (const float*)d_in[15],
        (float*)d_out, ws);
}

// Round 8
// 406.783 us; speedup vs baseline: 2.4005x; 2.4005x over previous
//
#include <hip/hip_runtime.h>

#define BB   2048
#define SS   256
#define NTOK (BB*SS)
#define FIN  3
#define CND  4
#define EMB  4
#define HID  64
#define NC   256
#define TPB  256   // block = 256 tokens = one batch row; lane-pair shares 2 tokens

typedef float f2 __attribute__((ext_vector_type(2)));
#define VFMA(a,b,c) __builtin_elementwise_fma(a,b,c)

static __device__ __forceinline__ f2 sp(float v) { f2 r; r.x = v; r.y = v; return r; }
static __device__ __forceinline__ f2 vrelu(f2 v) { return __builtin_elementwise_max(v, sp(0.0f)); }
static __device__ __forceinline__ f2 xor1(f2 v) {
    f2 r; r.x = __shfl_xor(v.x, 1, 64); r.y = __shfl_xor(v.y, 1, 64); return r;
}

// Fused LDS layout (float offsets; float4-aligned where float4-read). 44.7 KB.
#define OF_EW1 0
#define OF_EB1 448
#define OF_EW2 512
#define OF_EB2 4608
#define OF_EW3 4672
#define OF_EB3 4928
#define OF_CB  4944
#define OF_CC  5968
#define OF_DW1 6224
#define OF_DB1 6736
#define OF_DW2 6800
#define OF_DB2 10896
#define OF_DW3 10960
#define OF_DB3 11152
#define SMEM_F 11168

// Launch-bounds law (R3-R7 data): arch-VGPR cap = 256/W (unified file halved
// for AGPRs). W=6->40, W=4->64, W=3->84, W=2->128. This kernel's live set
// ~210 (VGPR+AGPR) -> ONLY W=2 is safe. W>=3 spills to scratch (R4: 13x,
// R7: 4.3x regressions, FETCH_SIZE balloons to GBs).
__global__ __launch_bounds__(TPB, 2) void vqvae_fused(
        const float* __restrict__ x, const float* __restrict__ mask,
        const float* __restrict__ cond,
        const float* __restrict__ ew1, const float* __restrict__ eb1,
        const float* __restrict__ ew2, const float* __restrict__ eb2,
        const float* __restrict__ ew3, const float* __restrict__ eb3,
        const float* __restrict__ cb,
        const float* __restrict__ dw1, const float* __restrict__ db1,
        const float* __restrict__ dw2, const float* __restrict__ db2,
        const float* __restrict__ dw3, const float* __restrict__ db3,
        float* __restrict__ out, float* __restrict__ ws) {
    __shared__ float smem[SMEM_F];
    const int tid = threadIdx.x;

    for (int i = tid; i < (FIN+CND)*HID; i += TPB) smem[OF_EW1+i] = ew1[i];
    for (int i = tid; i < HID;           i += TPB) smem[OF_EB1+i] = eb1[i];
    for (int i = tid; i < HID*HID;       i += TPB) smem[OF_EW2+i] = ew2[i];
    for (int i = tid; i < HID;           i += TPB) smem[OF_EB2+i] = eb2[i];
    for (int i = tid; i < HID*EMB;       i += TPB) smem[OF_EW3+i] = ew3[i];
    for (int i = tid; i < EMB;           i += TPB) smem[OF_EB3+i] = eb3[i];
    for (int i = tid; i < NC*EMB;        i += TPB) smem[OF_CB +i] = cb[i];
    for (int i = tid; i < (EMB+CND)*HID; i += TPB) smem[OF_DW1+i] = dw1[i];
    for (int i = tid; i < HID;           i += TPB) smem[OF_DB1+i] = db1[i];
    for (int i = tid; i < HID*HID;       i += TPB) smem[OF_DW2+i] = dw2[i];
    for (int i = tid; i < HID;           i += TPB) smem[OF_DB2+i] = db2[i];
    for (int i = tid; i < HID*FIN;       i += TPB) smem[OF_DW3+i] = dw3[i];
    for (int i = tid; i < FIN;           i += TPB) smem[OF_DB3+i] = db3[i];
    {   // cc from GLOBAL cb (no barrier dependency); validated order
        float c0 = cb[tid*EMB+0], c1 = cb[tid*EMB+1];
        float c2 = cb[tid*EMB+2], c3 = cb[tid*EMB+3];
        smem[OF_CC+tid] = ((c0*c0 + c1*c1) + c2*c2) + c3*c3;
    }
    __syncthreads();

    // lane-pair (2q, 2q+1) jointly processes tokens (t0, t1) packed as f2.
    const int p  = tid & 1;
    const int t0 = blockIdx.x * TPB + (tid & ~1);
    const int t1 = t0 + 1;
    f2 m; m.x = mask[t0]; m.y = mask[t1];

    // block == batch row -> cond wave-uniform (scalar loads)
    float cndv[CND];
    #pragma unroll
    for (int i = 0; i < CND; i++) cndv[i] = cond[blockIdx.x*CND + i];

    f2 xin[FIN+CND];
    #pragma unroll
    for (int i = 0; i < FIN; i++) { xin[i].x = x[t0*FIN + i] * m.x; xin[i].y = x[t1*FIN + i] * m.y; }
    #pragma unroll
    for (int i = 0; i < CND; i++) { xin[FIN+i].x = cndv[i] * m.x; xin[FIN+i].y = cndv[i] * m.y; }

    // ---- encoder L1: 7 -> 64, relu. Duplicated on both lanes (small);
    // per-output chain = validated tree ----
    f2 h[HID];
    #pragma unroll
    for (int j = 0; j < HID; j++) {
        f2 a = xin[0] * sp(smem[OF_EW1 + j]);
        #pragma unroll
        for (int i = 1; i < FIN+CND; i++) a = VFMA(xin[i], sp(smem[OF_EW1 + i*HID + j]), a);
        h[j] = vrelu(a + sp(smem[OF_EB1 + j]));
    }

    // ---- encoder L2 j-split: lane p owns jt in [8p, 8p+8). Full k-chain
    // per output j is the validated sequential tree (bit-exact). ----
    f2 tv[32];   // t for own 32 j's
    for (int g = 0; g < 8; g++) {
        const int jt = 8*p + g;
        f2 a0 = sp(0.f), a1 = sp(0.f), a2 = sp(0.f), a3 = sp(0.f);
        #pragma unroll
        for (int k = 0; k < HID; k++) {
            float4 w = *(const float4*)&smem[OF_EW2 + k*HID + jt*4];
            a0 = VFMA(h[k], sp(w.x), a0);
            a1 = VFMA(h[k], sp(w.y), a1);
            a2 = VFMA(h[k], sp(w.z), a2);
            a3 = VFMA(h[k], sp(w.w), a3);
        }
        float4 bb = *(const float4*)&smem[OF_EB2 + jt*4];
        tv[g*4+0] = vrelu(a0 + sp(bb.x));
        tv[g*4+1] = vrelu(a1 + sp(bb.y));
        tv[g*4+2] = vrelu(a2 + sp(bb.z));
        tv[g*4+3] = vrelu(a3 + sp(bb.w));
    }

    // ---- z-fold in EXACT validated order j=0..63 (argmin-critical).
    // phase 1: j=0..31 live on p==0 lanes; phase 2: j=32..63 on p==1. ----
    f2 z0 = sp(0.f), z1 = sp(0.f), z2 = sp(0.f), z3 = sp(0.f);
    for (int g = 0; g < 8; g++) {
        #pragma unroll
        for (int jj = 0; jj < 4; jj++) {
            f2 tmine = tv[g*4+jj];
            f2 toth  = xor1(tmine);
            f2 t = (p == 0) ? tmine : toth;
            float4 w = *(const float4*)&smem[OF_EW3 + (g*4+jj)*EMB];
            z0 = VFMA(t, sp(w.x), z0); z1 = VFMA(t, sp(w.y), z1);
            z2 = VFMA(t, sp(w.z), z2); z3 = VFMA(t, sp(w.w), z3);
        }
    }
    for (int g = 0; g < 8; g++) {
        #pragma unroll
        for (int jj = 0; jj < 4; jj++) {
            f2 tmine = tv[g*4+jj];
            f2 toth  = xor1(tmine);
            f2 t = (p == 1) ? tmine : toth;
            float4 w = *(const float4*)&smem[OF_EW3 + (32 + g*4+jj)*EMB];
            z0 = VFMA(t, sp(w.x), z0); z1 = VFMA(t, sp(w.y), z1);
            z2 = VFMA(t, sp(w.z), z2); z3 = VFMA(t, sp(w.w), z3);
        }
    }
    z0 = z0 + sp(smem[OF_EB3+0]); z1 = z1 + sp(smem[OF_EB3+1]);
    z2 = z2 + sp(smem[OF_EB3+2]); z3 = z3 + sp(smem[OF_EB3+3]);

    // ---- VQ code-split: lane p scans [128p, 128p+128). d bit-exact
    // (validated tree on bit-identical z); combine preserves np first-min ----
    const float A0 = z0.x, A1 = z1.x, A2 = z2.x, A3 = z3.x;
    const float B0 = z0.y, B1 = z1.y, B2 = z2.y, B3 = z3.y;
    const float zzA = ((A0*A0 + A1*A1) + A2*A2) + A3*A3;
    const float zzB = ((B0*B0 + B1*B1) + B2*B2) + B3*B3;
    float bestA = 3.4e38f, bestB = 3.4e38f;
    int   biA = 0, biB = 0;
    const int cbase = 128*p;
    #pragma unroll 4
    for (int cw = 0; cw < 128; cw++) {
        int ci = cbase + cw;
        float4 c = *(const float4*)&smem[OF_CB + ci*EMB];
        float cc = smem[OF_CC + ci];
        float dotA = A0 * c.x;
        dotA = fmaf(A1, c.y, dotA);
        dotA = fmaf(A2, c.z, dotA);
        dotA = fmaf(A3, c.w, dotA);
        float dA = (zzA - 2.0f*dotA) + cc;
        if (dA < bestA) { bestA = dA; biA = ci; }
        float dotB = B0 * c.x;
        dotB = fmaf(B1, c.y, dotB);
        dotB = fmaf(B2, c.z, dotB);
        dotB = fmaf(B3, c.w, dotB);
        float dB = (zzB - 2.0f*dotB) + cc;
        if (dB < bestB) { bestB = dB; biB = ci; }
    }
    {   // cross-pair combine: low half (p==0) wins ties via strict < on high
        float obA = __shfl_xor(bestA, 1, 64); int oiA = __shfl_xor(biA, 1, 64);
        float obB = __shfl_xor(bestB, 1, 64); int oiB = __shfl_xor(biB, 1, 64);
        float loA = (p==0)? bestA : obA;  int liA = (p==0)? biA : oiA;
        float hiA = (p==0)? obA : bestA;  int hiAi = (p==0)? oiA : biA;
        if (hiA < loA) { loA = hiA; liA = hiAi; }
        biA = liA;
        float loB = (p==0)? bestB : obB;  int liB = (p==0)? biB : oiB;
        float hiB = (p==0)? obB : bestB;  int hiBi = (p==0)? oiB : biB;
        if (hiB < loB) { loB = hiB; liB = hiBi; }
        biB = liB;
    }
    float4 qA = *(const float4*)&smem[OF_CB + biA*EMB];
    float4 qB = *(const float4*)&smem[OF_CB + biB*EMB];

    // ---- vq loss partial (pair-duplicated -> zero odd lanes) ----
    float e0 = A0-qA.x, e1 = A1-qA.y, e2 = A2-qA.z, e3 = A3-qA.w;
    float f0 = B0-qB.x, f1 = B1-qB.y, f2_ = B2-qB.z, f3 = B3-qB.w;
    float sq = (((e0*e0 + e1*e1) + e2*e2) + e3*e3)
             + (((f0*f0 + f1*f1) + f2_*f2_) + f3*f3);
    sq = (p == 0) ? sq : 0.0f;
    #pragma unroll
    for (int off = 32; off > 0; off >>= 1) sq += __shfl_down(sq, off, 64);
    if ((tid & 63) == 0) atomicAdd(ws, sq);

    if (p == 0) out[NTOK*FIN + 1 + t0] = (float)biA;
    else        out[NTOK*FIN + 1 + t1] = (float)biB;

    // ---- decoder input ----
    f2 zd[EMB+CND];
    zd[0].x = qA.x*m.x; zd[0].y = qB.x*m.y;
    zd[1].x = qA.y*m.x; zd[1].y = qB.y*m.y;
    zd[2].x = qA.z*m.x; zd[2].y = qB.z*m.y;
    zd[3].x = qA.w*m.x; zd[3].y = qB.w*m.y;
    #pragma unroll
    for (int i = 0; i < CND; i++) { zd[EMB+i].x = cndv[i]*m.x; zd[EMB+i].y = cndv[i]*m.y; }

    // ---- decoder L1: 8 -> 64, relu, duplicated (h reused) ----
    #pragma unroll
    for (int j = 0; j < HID; j++) {
        f2 a = zd[0] * sp(smem[OF_DW1 + j]);
        #pragma unroll
        for (int i = 1; i < EMB+CND; i++) a = VFMA(zd[i], sp(smem[OF_DW1 + i*HID + j]), a);
        h[j] = vrelu(a + sp(smem[OF_DB1 + j]));
    }

    // ---- decoder L2+L3 j-split (x_reco has ~4.8 abs threshold: reorder OK) ----
    f2 r0 = sp(0.f), r1 = sp(0.f), r2 = sp(0.f);
    for (int g = 0; g < 8; g++) {
        const int jt = 8*p + g;
        f2 a0 = sp(0.f), a1 = sp(0.f), a2 = sp(0.f), a3 = sp(0.f);
        #pragma unroll
        for (int k = 0; k < HID; k++) {
            float4 w = *(const float4*)&smem[OF_DW2 + k*HID + jt*4];
            a0 = VFMA(h[k], sp(w.x), a0);
            a1 = VFMA(h[k], sp(w.y), a1);
            a2 = VFMA(h[k], sp(w.z), a2);
            a3 = VFMA(h[k], sp(w.w), a3);
        }
        float4 bb = *(const float4*)&smem[OF_DB2 + jt*4];
        f2 tq0 = vrelu(a0 + sp(bb.x));
        f2 tq1 = vrelu(a1 + sp(bb.y));
        f2 tq2 = vrelu(a2 + sp(bb.z));
        f2 tq3 = vrelu(a3 + sp(bb.w));
        #pragma unroll
        for (int jj = 0; jj < 4; jj++) {
            f2 t = (jj==0)?tq0:(jj==1)?tq1:(jj==2)?tq2:tq3;
            int j = jt*4 + jj;
            r0 = VFMA(t, sp(smem[OF_DW3 + j*FIN + 0]), r0);
            r1 = VFMA(t, sp(smem[OF_DW3 + j*FIN + 1]), r1);
            r2 = VFMA(t, sp(smem[OF_DW3 + j*FIN + 2]), r2);
        }
    }
    r0 = r0 + xor1(r0);   // combine pair halves
    r1 = r1 + xor1(r1);
    r2 = r2 + xor1(r2);
    r0 = r0 + sp(smem[OF_DB3+0]);
    r1 = r1 + sp(smem[OF_DB3+1]);
    r2 = r2 + sp(smem[OF_DB3+2]);

    if (p == 0) {
        out[t0*FIN + 0] = r0.x;
        out[t0*FIN + 1] = r1.x;
        out[t0*FIN + 2] = r2.x;
    } else {
        out[t1*FIN + 0] = r0.y;
        out[t1*FIN + 1] = r1.y;
        out[t1*FIN + 2] = r2.y;
    }

    // ---- fused finalize: last block writes vq_loss ----
    __syncthreads();
    if (tid == 0) {
        __threadfence();
        unsigned int old = atomicAdd((unsigned int*)(ws + 1), 1u);
        if (old == gridDim.x - 1) {
            __threadfence();
            float total = atomicAdd(ws, 0.0f);
            out[NTOK*FIN] = 1.25f * total * (1.0f / (float)(NTOK*EMB));
        }
    }
}

extern "C" void kernel_launch(void* const* d_in, const int* in_sizes, int n_in,
                              void* d_out, int out_size, void* d_ws, size_t ws_size,
                              hipStream_t stream) {
    (void)in_sizes; (void)n_in; (void)ws_size; (void)out_size;
    float* ws = (float*)d_ws;
    hipMemsetAsync(ws, 0, 2*sizeof(float), stream);  // loss accum + done counter

    vqvae_fused<<<NTOK/TPB, TPB, 0, stream>>>(
        (const float*)d_in[0], (const float*)d_in[1], (const float*)d_in[2],
        (const float*)d_in[3], (const float*)d_in[4], (const float*)d_in[5],
        (const float*)d_in[6], (const float*)d_in[7], (const float*)d_in[8],
        (const float*)d_in[9], (const float*)d_in[10], (const float*)d_in[11],
        (const float*)d_in[12], (const float*)d_in[13], (const float*)d_in[14],
        (const float*)d_in[15],
        (float*)d_out, ws);
}